// Round 4
// baseline (335.773 us; speedup 1.0000x reference)
//
#include <hip/hip_runtime.h>
#include <hip/hip_bf16.h>

#define BB 32
#define LL 128
#define DD 400
#define KK 40
#define EE 416   // e padded to 13*32
#define SDN 50   // d-slot count (400/8)
#define SEN 52   // e-slot count (416/8)

typedef __attribute__((ext_vector_type(8)))  short  bfrag;   // 8 bf16 = 4 VGPRs
typedef __attribute__((ext_vector_type(16))) float  ffrag;   // 16 fp32 acc

static __device__ __forceinline__ short f2bf(float f) {
    union { float f; unsigned u; } v; v.f = f;
    unsigned r = (v.u + 0x7FFF + ((v.u >> 16) & 1)) >> 16;
    return (short)r;
}

#define MFMA32(a, b, c) __builtin_amdgcn_mfma_f32_32x32x16_bf16((a), (b), (c), 0, 0, 0)

static __device__ __forceinline__ void fzero(ffrag& f) {
#pragma unroll
    for (int r = 0; r < 16; ++r) f[r] = 0.f;
}

// ---------------------------------------------------------------------------
// Fused prep: Hslots[b][sd][h][8], Cslots[b][se][c][8] (zero-pad e>=400),
//             Uslots[k][sd][e][8] (zero-pad e>=400).
// ---------------------------------------------------------------------------
__global__ __launch_bounds__(256) void p_prep(
    const float* __restrict__ H, const float* __restrict__ C,
    const float* __restrict__ U,
    short* __restrict__ Hs, short* __restrict__ Cs, short* __restrict__ Us)
{
    int id = blockIdx.x * 256 + threadIdx.x;
    if (id < BB*SDN*LL) {
        int b = id / (SDN*LL); int r = id % (SDN*LL);
        int sd = r / LL; int h = r % LL;
        const float* src = H + ((size_t)(b*LL + h))*DD + sd*8;
        bfrag v;
#pragma unroll
        for (int j = 0; j < 8; ++j) v[j] = f2bf(src[j]);
        *(bfrag*)(Hs + (size_t)id*8) = v;
    } else if (id < BB*SDN*LL + BB*SEN*LL) {
        id -= BB*SDN*LL;
        int b = id / (SEN*LL); int r = id % (SEN*LL);
        int se = r / LL; int c = r % LL;
        bfrag v;
#pragma unroll
        for (int j = 0; j < 8; ++j) {
            int e = se*8 + j;
            v[j] = (e < DD) ? f2bf(C[((size_t)(b*LL + c))*DD + e]) : (short)0;
        }
        *(bfrag*)(Cs + (size_t)id*8) = v;
    } else {
        id -= BB*SDN*LL + BB*SEN*LL;      // < 40*50*416
        int k = id / (SDN*EE); int r = id % (SDN*EE);
        int sd = r / EE; int e = r % EE;
        bfrag v;
#pragma unroll
        for (int j = 0; j < 8; ++j)
            v[j] = (e < DD) ? f2bf(U[((size_t)k*DD + sd*8 + j)*DD + e]) : (short)0;
        *(bfrag*)(Us + (size_t)id*8) = v;
    }
}

// ---------------------------------------------------------------------------
// SD/SE (unchanged — verified round 2, off the critical path).
// ---------------------------------------------------------------------------
__global__ __launch_bounds__(256) void k_sdse(
    const float* __restrict__ H, const float* __restrict__ C,
    const float* __restrict__ Wd, const float* __restrict__ We,
    float* __restrict__ SD, float* __restrict__ SE)
{
    const int b   = blockIdx.x;
    const int rg  = blockIdx.y;
    const int srcC = blockIdx.z;
    const int t = threadIdx.x;

    __shared__ float Wl[KK*DD];      // 64 KB
    {
        const float4* Wsrc = (const float4*)(srcC ? We : Wd);
        for (int i = t; i < KK*DD/4; i += 256) ((float4*)Wl)[i] = Wsrc[i];
    }
    __syncthreads();

    const int task = t >> 3;
    const int p    = t & 7;
    const int row  = rg*32 + task;
    const float* X = (srcC ? C : H) + ((size_t)(b*LL + row))*DD + p*50;

    float2 x[25];
#pragma unroll
    for (int i = 0; i < 25; ++i) x[i] = ((const float2*)X)[i];

    float* out = (srcC ? SE : SD) + (size_t)b*KK*LL + row;
    const float* Wb = Wl + p*50;

    for (int k = 0; k < KK; ++k) {
        const float2* wp = (const float2*)(Wb + k*DD);
        float s0 = 0.f, s1 = 0.f;
#pragma unroll
        for (int i = 0; i < 24; i += 2) {
            float2 w0 = wp[i], w1 = wp[i+1];
            s0 = fmaf(x[i].x,   w0.x, s0); s0 = fmaf(x[i].y,   w0.y, s0);
            s1 = fmaf(x[i+1].x, w1.x, s1); s1 = fmaf(x[i+1].y, w1.y, s1);
        }
        { float2 w0 = wp[24]; s0 = fmaf(x[24].x, w0.x, s0); s0 = fmaf(x[24].y, w0.y, s0); }
        float s = s0 + s1;
        s += __shfl_xor(s, 1); s += __shfl_xor(s, 2); s += __shfl_xor(s, 4);
        if (p == 0) out[k*LL] = s;
    }
}

// T-write: scatter one 32x32 T-tile (rows = e, cols = h) into the ping-pong
// buffer in phase-2 A-fragment layout [s_e][h][8]. Skips e>=400.
static __device__ __forceinline__ void t_write(
    short* __restrict__ Ping, const ffrag& T, int et, int ht, int l31, int kh)
{
#pragma unroll
    for (int r = 0; r < 16; r += 2) {
        const int e_loc = 32*et + (r&3) + 8*(r>>2) + 4*kh;
        if (e_loc < DD) {
            unsigned lo = (unsigned short)f2bf(T[r]);
            unsigned hi = (unsigned short)f2bf(T[r+1]);
            *(unsigned*)(&Ping[((size_t)(e_loc>>3)*LL + 32*ht + l31)*8 + (e_loc&7)]) =
                lo | (hi << 16);
        }
    }
}

// ---------------------------------------------------------------------------
// Main MFMA kernel, round 4 (= round 3 minus Cst; LDS 102.4 KB <= proven
// 128 KB envelope).
//   grid (8 g, 32 b) = 256 blocks = 1/CU, 1024 thr = 16 waves.
//   LDS Ping ping-pongs between Hs[b] (staged per k) and Tbuf (T[e<400][h]).
//   Phase 1: wave w<13 owns e-tile w: 1 Us frag from L2 (1x per block,
//            XCD-resident) + 4 Hs frags from LDS per K-step, 4 MFMA.
//   Phase 2: wave (ht2,ct) computes one 32x32 S-tile; A from LDS-T,
//            B streamed from L2 with 2-deep prefetch. 25 K-steps (e<400).
//   4 barriers/k; exp accumulated in regs; slice written non-atomic.
// ---------------------------------------------------------------------------
__global__ __launch_bounds__(1024) void k_mfma(
    const short* __restrict__ Hs, const short* __restrict__ Cs,
    const short* __restrict__ Us,
    const float* __restrict__ SD, const float* __restrict__ SE,
    const float* __restrict__ bvec, const float* __restrict__ mask,
    const int* __restrict__ heads, const int* __restrict__ tags,
    float* __restrict__ A8, float* __restrict__ tgt)
{
    const int g  = blockIdx.x;     // k-group (XCD via linear%8)
    const int b  = blockIdx.y;
    const int t  = threadIdx.x;
    const int w  = t >> 6;         // 0..15
    const int l31 = t & 31;
    const int kh  = (t >> 5) & 1;  // K-half of MFMA operands

    __shared__ short Ping[SDN*LL*8];    // 102,400 B : Hs stage <-> Tbuf

    const size_t hsB = (size_t)b * SDN * LL;
    const size_t csB = (size_t)b * SEN * LL;

    // ---- phase-2 roles & k-invariant epilogue constants ----
    const int ht2 = w >> 2;            // h-tile 0..3
    const int ct  = w & 3;             // c-tile 0..3
    const int hbase = 32*ht2 + 4*kh;
    const int c0 = 32*ct + l31;
    const float mc0 = mask[b*LL + c0];
    const int head0 = heads[b*LL + c0];
    const int tag0  = tags[b*LL + c0];
    unsigned vb = 0;
#pragma unroll
    for (int r = 0; r < 16; ++r) {
        const int hr = hbase + (r&3) + 8*(r>>2);
        if (mask[b*LL + hr] != 0.f && mc0 != 0.f && hr != c0) vb |= 1u << r;
    }

    ffrag E; fzero(E);

    for (int kk = 0; kk < 5; ++kk) {
        const int k = g + 8*kk;

        __syncthreads();   // prev phase 2 done reading Ping

        // ---- stage Hs[b] -> Ping (102.4 KB straight copy) ----
        {
            const uint4* src = (const uint4*)(Hs + hsB*8);
            uint4* dst = (uint4*)Ping;
            for (int i = t; i < SDN*LL*8*2/16; i += 1024) dst[i] = src[i];
        }
        __syncthreads();

        // ---- Phase 1: wave w<13 computes T[e-tile w][all 128 h] ----
        ffrag T0, T1, T2, T3;
        if (w < 13) {
            fzero(T0); fzero(T1); fzero(T2); fzero(T3);
            const int et = w;
            const short* up = Us + (((size_t)k*SDN + kh)*EE + 32*et + l31)*8;
            const short* hb = Ping + ((size_t)kh*LL + l31)*8;
#define UPF(j)    (*(const bfrag*)(up + (size_t)(j)*(2*EE*8)))
#define HPF(j,ht) (*(const bfrag*)(hb + ((size_t)(2*(j))*LL + 32*(ht))*8))
            bfrag a0 = UPF(0), a1 = UPF(1);
#pragma unroll 1
            for (int j = 0; j < 23; ++j) {
                bfrag an = UPF(j+2);
                bfrag b0 = HPF(j,0), b1 = HPF(j,1), b2 = HPF(j,2), b3 = HPF(j,3);
                T0 = MFMA32(a0, b0, T0); T1 = MFMA32(a0, b1, T1);
                T2 = MFMA32(a0, b2, T2); T3 = MFMA32(a0, b3, T3);
                a0 = a1; a1 = an;
            }
            {   // j = 23, 24
                bfrag b0 = HPF(23,0), b1 = HPF(23,1), b2 = HPF(23,2), b3 = HPF(23,3);
                T0 = MFMA32(a0, b0, T0); T1 = MFMA32(a0, b1, T1);
                T2 = MFMA32(a0, b2, T2); T3 = MFMA32(a0, b3, T3);
                b0 = HPF(24,0); b1 = HPF(24,1); b2 = HPF(24,2); b3 = HPF(24,3);
                T0 = MFMA32(a1, b0, T0); T1 = MFMA32(a1, b1, T1);
                T2 = MFMA32(a1, b2, T2); T3 = MFMA32(a1, b3, T3);
            }
#undef UPF
#undef HPF
        }
        __syncthreads();   // all waves done reading Ping-as-Hs

        if (w < 13) {
            t_write(Ping, T0, w, 0, l31, kh);
            t_write(Ping, T1, w, 1, l31, kh);
            t_write(Ping, T2, w, 2, l31, kh);
            t_write(Ping, T3, w, 3, l31, kh);
        }
        __syncthreads();   // Tbuf complete

        // ---- Phase 2: one 32x32 S-tile per wave, 25 K-steps (e<400) ----
        ffrag S; fzero(S);
        const short* ta = Ping + ((size_t)kh*LL + 32*ht2 + l31)*8;
        const short* cp = Cs + (csB + (size_t)kh*LL + 32*ct + l31)*8;
#define TAF(j) (*(const bfrag*)(ta + (size_t)(2*(j))*(LL*8)))
#define CPF(j) (*(const bfrag*)(cp + (size_t)(2*(j))*(LL*8)))
        bfrag c0f = CPF(0), c1f = CPF(1);
#pragma unroll 1
        for (int j = 0; j < 23; ++j) {
            bfrag cn = CPF(j+2);
            S = MFMA32(TAF(j), c0f, S);
            c0f = c1f; c1f = cn;
        }
        S = MFMA32(TAF(23), c0f, S);
        S = MFMA32(TAF(24), c1f, S);
#undef TAF
#undef CPF

        // ---- per-k epilogue ----
        const float bk = bvec[k];
        const float* SDb = SD + ((size_t)b*KK + k)*LL;
        const float sev = SE[((size_t)b*KK + k)*LL + c0];
#pragma unroll
        for (int r = 0; r < 16; ++r) {
            const int hr = hbase + (r&3) + 8*(r>>2);
            const float ev = S[r] + SDb[hr] + sev + bk;
            if ((vb >> r) & 1) {
                E[r] += __expf(ev);
                if (c0 >= 1 && tag0 == k && head0 == hr) atomicAdd(&tgt[b], ev);
            }
        }
    }

    // ---- write slice g (exclusive ownership, non-atomic) ----
    float* Ab = A8 + ((size_t)(g*BB + b))*LL*LL;
#pragma unroll
    for (int r = 0; r < 16; ++r) {
        const int hr = hbase + (r&3) + 8*(r>>2);
        Ab[hr*LL + c0] = E[r];
    }
}

// ---------------------------------------------------------------------------
// Register-resident LU logdet (unchanged).
// ---------------------------------------------------------------------------
__global__ __launch_bounds__(256) void k_logdet(
    const float* __restrict__ A8, const int* __restrict__ lengths,
    const float* __restrict__ tgt, float* __restrict__ out)
{
    const int b = blockIdx.x;
    const int t = threadIdx.x;
    const int rg = t >> 4;
    const int cg = t & 15;

    __shared__ float As[LL*LL];
    __shared__ float Dg[128];
    __shared__ float Lbuf[128];
    __shared__ float Ubuf[128];
    __shared__ float red[256];

    const float4* A4 = (const float4*)A8;
    for (int f4 = t; f4 < 4096; f4 += 256) {
        float4 s = make_float4(0.f, 0.f, 0.f, 0.f);
#pragma unroll
        for (int g = 0; g < 8; ++g) {
            float4 v = A4[((size_t)(g*BB + b))*4096 + f4];
            s.x += v.x; s.y += v.y; s.z += v.z; s.w += v.w;
        }
        ((float4*)As)[f4] = s;
    }
    __syncthreads();

    if (t < 128) {
        float s = 0.f;
        for (int hr = 0; hr < LL; ++hr) s += As[hr*LL + t];
        Dg[t] = s * (1.0f + 1e-4f) + 1e-6f;
    }
    __syncthreads();

    const int n1 = lengths[b] - 1;
    float m[8][8];
#pragma unroll
    for (int r = 0; r < 8; ++r) {
        const int i = 8*rg + r;
#pragma unroll
        for (int c = 0; c < 8; ++c) {
            const int j = 8*cg + c;
            float v;
            if (i < n1 && j < n1)
                v = ((i == j) ? Dg[i+1] : 0.f) - As[(i+1)*LL + (j+1)];
            else
                v = (i == j) ? 1.f : 0.f;
            m[r][c] = v;
        }
    }
    __syncthreads();

    for (int j = 0; j < 127; ++j) {
        const int jg = j >> 3, jl = j & 7;
        if (cg == jg) {
#pragma unroll
            for (int c = 0; c < 8; ++c) {
                if (c == jl) {
#pragma unroll
                    for (int r = 0; r < 8; ++r) Lbuf[8*rg + r] = m[r][c];
                }
            }
        }
        if (rg == jg) {
#pragma unroll
            for (int r = 0; r < 8; ++r) {
                if (r == jl) {
#pragma unroll
                    for (int c = 0; c < 8; ++c) Ubuf[8*cg + c] = m[r][c];
                }
            }
        }
        __syncthreads();

        const float piv = Lbuf[j];
        if (t == j) Dg[j] = piv;
        const float rp = 1.0f / piv;
        float lr[8], ur[8];
#pragma unroll
        for (int r = 0; r < 8; ++r) lr[r] = Lbuf[8*rg + r] * rp;
#pragma unroll
        for (int c = 0; c < 8; ++c) ur[c] = Ubuf[8*cg + c];
#pragma unroll
        for (int r = 0; r < 8; ++r)
#pragma unroll
            for (int c = 0; c < 8; ++c)
                m[r][c] = fmaf(-lr[r], ur[c], m[r][c]);
        __syncthreads();
    }

    float lsum = 0.f;
    if (t < 127) lsum = logf(Dg[t]);
    red[t] = lsum;
    __syncthreads();
    for (int off = 128; off >= 1; off >>= 1) {
        if (t < off) red[t] += red[t + off];
        __syncthreads();
    }
    if (t == 0) out[b] = red[0] - tgt[b];
}

// ---------------------------------------------------------------------------
extern "C" void kernel_launch(void* const* d_in, const int* in_sizes, int n_in,
                              void* d_out, int out_size, void* d_ws, size_t ws_size,
                              hipStream_t stream) {
    const float* H    = (const float*)d_in[0];
    const float* C    = (const float*)d_in[1];
    const float* Wd   = (const float*)d_in[2];
    const float* We   = (const float*)d_in[3];
    const float* U    = (const float*)d_in[4];
    const float* bv   = (const float*)d_in[5];
    const float* mask = (const float*)d_in[6];
    const int* heads  = (const int*)d_in[7];
    const int* tags   = (const int*)d_in[8];
    const int* lens   = (const int*)d_in[9];
    float* out = (float*)d_out;

    // workspace layout
    char* p = (char*)d_ws;
    float* A8  = (float*)p;                 p += (size_t)8*BB*LL*LL*4;      // 16.78 MB
    float* tgt = (float*)p;                 p += 32*4;
    float* SDp = (float*)p;                 p += (size_t)BB*KK*LL*4;
    float* SEp = (float*)p;                 p += (size_t)BB*KK*LL*4;
    short* Hsp = (short*)p;                 p += (size_t)BB*SDN*LL*8*2;
    short* Csp = (short*)p;                 p += (size_t)BB*SEN*LL*8*2;
    short* Usp = (short*)p;                 p += (size_t)KK*SDN*EE*8*2;

    hipMemsetAsync(tgt, 0, 32*4, stream);

    // (BB*SDN*LL + BB*SEN*LL + KK*SDN*EE) / 256 = 4882 exactly
    p_prep<<<dim3(4882), 256, 0, stream>>>(H, C, U, Hsp, Csp, Usp);
    k_sdse<<<dim3(BB, 4, 2), 256, 0, stream>>>(H, C, Wd, We, SDp, SEp);
    k_mfma<<<dim3(8, BB), 1024, 0, stream>>>(Hsp, Csp, Usp, SDp, SEp, bv, mask,
                                             heads, tags, A8, tgt);
    k_logdet<<<dim3(BB), 256, 0, stream>>>(A8, lens, tgt, out);
}